// Round 6
// baseline (3523.796 us; speedup 1.0000x reference)
//
#include <hip/hip_runtime.h>
#include <hip/hip_bf16.h>

// LSTM_Net round 16: XCD-local domains, hardened (no unverified primitives).
// r15 (no result - hang or infra) stacked three unknowns: sc0-scope sync,
// XCC role-grab, 96KB LDS pad. r16 removes the most likely hang source
// (sc0 loads possibly not bypassing L1 -> stale-flag spin):
//   - ALL flags: sc1 store + AGENT_LD poll (r10-r14 proven combo).
//   - h2 ring (L1 self-recurrence): PLAIN stores + PLAIN loads. L1 cache is
//     write-through so stores land in the local XCD L2; consumers same-XCD;
//     full-T ring -> fresh addresses -> no stale-L1; kernel-boundary
//     invalidation covers iterations. This is the data-locality win.
//   - h1: single sc1 ring h1x (L0 self-reads it plain: correct whether or
//     not sc1 store leaves an L2 copy). Saves 24MB vs r15.
//   - L1 k-loop order: issue h1x loads (MALL) first, h2 local second, MFMA
//     h2-half (streamed B) while h1x lands, then h1-half (pinned B).
// Kept from r15: XCC_ID role grab + 96KB pad (1 WG/CU => 32 WG/XCD),
// 8 domains = (layer, batch-group16), pinned weights, batched A-loads,
// heaters. Pre-registered: hang again => XCC grab or LDS pad at fault.
// ctrs (ints): [0..7] role ctrs, fs[xcd]=ctrs[256+xcd*64+..24) self flags,
// fx[g]=ctrs[1024+g*64+..24) cross h1 flags, [2048] done.

#define B_  64
#define T_  256
#define IN_ 64
#define H_  768
#define G_  3072   // 4*H
#define K0_ 832    // IN_ + H_
#define K1_ 1536   // 2*H_
#define NWGT 256
#define GSLOT_ 12288   // per (t,group) ring slot elems = 96cbw * 16rows * 8cols

typedef __bf16 bf16_t;
typedef bf16_t bf16x8 __attribute__((ext_vector_type(8)));
typedef float  f32x4  __attribute__((ext_vector_type(4)));

__device__ __forceinline__ unsigned short f2bf(float f) {
    union { float f; unsigned u; } v; v.f = f;
    unsigned r = v.u + 0x7FFFu + ((v.u >> 16) & 1u);
    return (unsigned short)(r >> 16);
}
__device__ __forceinline__ float fast_sigm(float x) {
    float e = __builtin_amdgcn_exp2f(-1.44269504f * x);
    return __builtin_amdgcn_rcpf(1.0f + e);
}
__device__ __forceinline__ float fast_tanh(float x) {
    float e = __builtin_amdgcn_exp2f(2.88539008f * x);
    return (e - 1.0f) * __builtin_amdgcn_rcpf(e + 1.0f);
}
// MALL-coherent store (cross-die visibility) — proven r9-r14
__device__ __forceinline__ void st_llc_u32(unsigned* p, unsigned v) {
    asm volatile("global_store_dword %0, %1, off sc1" :: "v"(p), "v"(v) : "memory");
}
#define MFMA16(a, b, c) __builtin_amdgcn_mfma_f32_16x16x32_bf16((a), (b), (c), 0, 0, 0)
#define AGENT_LD(p) __hip_atomic_load((p), __ATOMIC_RELAXED, __HIP_MEMORY_SCOPE_AGENT)
#define PIN8(v) asm volatile("" : "+v"(v))

// ---------------- prep ----------------
__global__ __launch_bounds__(256) void prep_kernel(
    const float* __restrict__ x,
    const float* __restrict__ Wih0, const float* __restrict__ Whh0,
    const float* __restrict__ bih0, const float* __restrict__ bhh0,
    const float* __restrict__ Wih1, const float* __restrict__ Whh1,
    const float* __restrict__ bih1, const float* __restrict__ bhh1,
    unsigned short* __restrict__ xsT,    // [T][B][64]
    unsigned short* __restrict__ W0cat,  // [3072][832]
    unsigned short* __restrict__ W1cat,  // [3072][1536]
    float* __restrict__ bias0, float* __restrict__ bias1,
    int* __restrict__ ctrs)              // [16384]
{
    int i = blockIdx.x * blockDim.x + threadIdx.x;
    int stride = gridDim.x * blockDim.x;
    for (int j = i; j < B_ * T_ * IN_; j += stride) {
        int b = j >> 14;
        int t = (j >> 6) & (T_ - 1);
        int k = j & (IN_ - 1);
        xsT[(((size_t)t * B_) + b) * IN_ + k] = f2bf(x[j] * (1.0f / 1.5f));
    }
    for (int j = i; j < G_ * IN_; j += stride) {
        int r = j >> 6; int k = j & 63;
        W0cat[(size_t)r * K0_ + k] = f2bf(Wih0[j]);
    }
    for (int j = i; j < G_ * H_; j += stride) {
        int r = j / H_; int k = j - r * H_;
        W0cat[(size_t)r * K0_ + IN_ + k] = f2bf(Whh0[j]);
        W1cat[(size_t)r * K1_ + k]       = f2bf(Wih1[j]);
        W1cat[(size_t)r * K1_ + H_ + k]  = f2bf(Whh1[j]);
    }
    for (int j = i; j < G_; j += stride) {
        bias0[j] = bih0[j] + bhh0[j];
        bias1[j] = bih1[j] + bhh1[j];
    }
    for (int j = i; j < 16384; j += stride) ctrs[j] = 0;
}

// ---------------- persistent XCD-domain recurrence ----------------
__global__ __launch_bounds__(256, 1) void lstm_persistent(
    const unsigned short* __restrict__ xsT,
    const unsigned short* __restrict__ W0cat,
    const unsigned short* __restrict__ W1cat,
    const float* __restrict__ bias0, const float* __restrict__ bias1,
    unsigned short* __restrict__ h1x,    // [T][4g][96cbw][16][8] sc1 (cross)
    unsigned short* __restrict__ h2loc,  // [T][4g][96cbw][16][8] plain (local)
    float* __restrict__ hf32,            // [B][H] fp32 (t = T-1)
    int* __restrict__ ctrs)
{
    __shared__ unsigned short ldsb[4][16][8];
    __shared__ char ldspad[96 * 1024];   // forces 1 WG/CU -> 32 WGs/XCD
    __shared__ int role_s;

    const int tid  = threadIdx.x;
    const int lane = tid & 63;
    const int wave = tid >> 6;

    // keep-alive for ldspad (condition never true at runtime)
    if (blockIdx.x == 0x7fffffffu) ldspad[tid] = (char)tid;

    int xcd;
    asm volatile("s_getreg_b32 %0, hwreg(HW_REG_XCC_ID)" : "=s"(xcd));
    xcd &= 7;

    if (tid == 0) role_s = atomicAdd(&ctrs[xcd], 1);
    __syncthreads();
    const int role = role_s;

    int* done = &ctrs[2048];

    // ---------- heater roles: pin GFX clock; poll dedicated done line ------
    if (role >= 24) {
        float a = 1.0f + (float)tid * 1e-7f;
        const float bm = 1.0000001f, cm = 1e-9f;
        for (;;) {
            for (int i = 0; i < 2048; i++)
                a = __builtin_fmaf(a, bm, cm);
            asm volatile("" : "+v"(a));
            int d = 0;
            if (lane == 0) d = AGENT_LD(done);
            d = __builtin_amdgcn_readfirstlane(d);
            if (d != 0) break;
        }
        return;
    }

    const int l  = xcd & 1;          // layer handled by this XCD
    const int g  = xcd >> 1;         // batch group (16 rows)
    const int m0 = g * 16;           // group's batch-row base
    const int cbw = role * 4 + wave; // H-col block 0..95 (8 cols each)
    const int c0  = cbw * 8;
    const int frow = lane & 15;
    const int q    = lane >> 4;
    const int kof  = q * 8;

    int fidx = lane; if (fidx >= 48) fidx -= 48; if (fidx >= 24) fidx -= 24;
    int* fself = &ctrs[256 + xcd * 64];   // my domain's 24 self flags
    int* fx    = &ctrs[1024 + g * 64];    // cross-die h1 flags for group g

    const unsigned short* Wc = l ? W1cat : W0cat;
    const int Kc = l ? K1_ : K0_;
    int q0 = frow >> 3, col0 = c0 + (frow & 7);
    const unsigned short* Bp0 = Wc + (size_t)(q0 * H_ + col0) * Kc + kof;       // gates i,f
    const unsigned short* Bp1 = Wc + (size_t)((2 + q0) * H_ + col0) * Kc + kof; // gates g,o

    const float* bias = l ? bias1 : bias0;
    const bool lowhalf = (lane & 15) < 8;
    const int ecol = c0 + (lane & 7);
    float bi = 0.f, bff = 0.f, bg = 0.f, bo = 0.f;
    if (lowhalf) {
        bi  = bias[0 * H_ + ecol];
        bff = bias[1 * H_ + ecol];
        bg  = bias[2 * H_ + ecol];
        bo  = bias[3 * H_ + ecol];
    }
    float creg[4] = {0.f, 0.f, 0.f, 0.f};

    // consumer: chunk kj reads col-block (4kj+q), rows frow, 8 cols
    const size_t aoff = (size_t)q * 128 + (size_t)frow * 8;
    // producer: wave owns block cbw; dword lane -> (row=lane>>2, col=(lane&3)*2)
    const size_t stoff_e = (size_t)cbw * 128 + (size_t)(lane >> 2) * 8
                         + (size_t)(lane & 3) * 2;

    if (l == 0) {
        // ------------- layer 0 domain: superstep s computes h1[s] -----------
        bf16x8 Bw0[26], Bw1[26];
        #pragma unroll
        for (int k = 0; k < 26; k++) {
            Bw0[k] = *(const bf16x8*)(Bp0 + k * 32);
            Bw1[k] = *(const bf16x8*)(Bp1 + k * 32);
        }
        #pragma unroll
        for (int k = 0; k < 26; k++) { PIN8(Bw0[k]); PIN8(Bw1[k]); }
        for (int s = 0; s < T_; ++s) {
            f32x4 acc0 = {0.f, 0.f, 0.f, 0.f};
            f32x4 acc1 = {0.f, 0.f, 0.f, 0.f};
            {
                const unsigned short* xsp =
                    xsT + ((size_t)s * B_ + m0 + frow) * IN_ + kof;
                bf16x8 ax0 = *(const bf16x8*)(xsp);
                bf16x8 ax1 = *(const bf16x8*)(xsp + 32);
                acc0 = MFMA16(ax0, Bw0[0], acc0);
                acc1 = MFMA16(ax0, Bw1[0], acc1);
                acc0 = MFMA16(ax1, Bw0[1], acc0);
                acc1 = MFMA16(ax1, Bw1[1], acc1);
            }
            if (s > 0) {
                if (wave == 0) {   // all 24 self flags >= s (AGENT poll)
                    const int* fp = &fself[fidx];
                    for (;;) {
                        int v = AGENT_LD(fp);
                        if (__all(v >= s)) break;
                        __builtin_amdgcn_s_sleep(1);
                    }
                }
                __syncthreads();
                const unsigned short* hr =
                    h1x + ((size_t)(s - 1) * 4 + g) * GSLOT_ + aoff;
                bf16x8 a[24];
                #pragma unroll
                for (int kj = 0; kj < 24; kj++)
                    a[kj] = *(const bf16x8*)(hr + kj * 512);
                #pragma unroll
                for (int kj = 0; kj < 24; kj++) {
                    acc0 = MFMA16(a[kj], Bw0[kj + 2], acc0);
                    acc1 = MFMA16(a[kj], Bw1[kj + 2], acc1);
                }
            }
            f32x4 pacc0, pacc1;
            #pragma unroll
            for (int j = 0; j < 4; j++) {
                pacc0[j] = __shfl_xor(acc0[j], 8);
                pacc1[j] = __shfl_xor(acc1[j], 8);
            }
            if (lowhalf) {
                #pragma unroll
                for (int j = 0; j < 4; j++) {
                    float pi = acc0[j]  + bi;
                    float pf = pacc0[j] + bff;
                    float pg = acc1[j]  + bg;
                    float po = pacc1[j] + bo;
                    float cn = fast_sigm(pf) * creg[j] + fast_sigm(pi) * fast_tanh(pg);
                    float hn = fast_sigm(po) * fast_tanh(cn);
                    creg[j] = cn;
                    ldsb[wave][q * 4 + j][lane & 7] = f2bf(hn);
                }
            }
            unsigned v = ((const unsigned*)&ldsb[wave][0][0])[lane];
            st_llc_u32((unsigned*)(h1x + ((size_t)s * 4 + g) * GSLOT_ + stoff_e), v);
            asm volatile("s_waitcnt vmcnt(0)" ::: "memory");
            __syncthreads();   // all 4 waves' stores drained
            if (tid == 0) {
                st_llc_u32((unsigned*)&fself[role], (unsigned)(s + 1));  // own domain
                st_llc_u32((unsigned*)&fx[role],    (unsigned)(s + 1));  // L1 domain
            }
        }
    } else {
        // ------------- layer 1 domain: superstep s computes h2[s-1] ---------
        bf16x8 Bw0[24], Bw1[24];   // h1-part weights pinned
        #pragma unroll
        for (int k = 0; k < 24; k++) {
            Bw0[k] = *(const bf16x8*)(Bp0 + k * 32);
            Bw1[k] = *(const bf16x8*)(Bp1 + k * 32);
        }
        #pragma unroll
        for (int k = 0; k < 24; k++) { PIN8(Bw0[k]); PIN8(Bw1[k]); }
        for (int s = 1; s <= T_; ++s) {
            const int t = s - 1;
            if (wave == 0) {   // h1[t] ready cross-die: fx >= t+1 = s
                const int* fp = &fx[fidx];
                for (;;) {
                    int v = AGENT_LD(fp);
                    if (__all(v >= s)) break;
                    __builtin_amdgcn_s_sleep(1);
                }
            }
            if (wave == 1 && t > 0) {   // h2[t-1] ready local: fself >= t
                const int* fp = &fself[fidx];
                for (;;) {
                    int v = AGENT_LD(fp);
                    if (__all(v >= t)) break;
                    __builtin_amdgcn_s_sleep(1);
                }
            }
            __syncthreads();
            f32x4 acc0 = {0.f, 0.f, 0.f, 0.f};
            f32x4 acc1 = {0.f, 0.f, 0.f, 0.f};
            const unsigned short* h1r = h1x + ((size_t)t * 4 + g) * GSLOT_ + aoff;
            if (t > 0) {
                const unsigned short* h2r =
                    h2loc + ((size_t)(t - 1) * 4 + g) * GSLOT_ + aoff;
                // issue h1x (MALL, long pole) first, then local h2
                bf16x8 a1[24];
                #pragma unroll
                for (int ki = 0; ki < 24; ki++)
                    a1[ki] = *(const bf16x8*)(h1r + ki * 512);
                bf16x8 a2[24];
                #pragma unroll
                for (int ki = 0; ki < 24; ki++)
                    a2[ki] = *(const bf16x8*)(h2r + ki * 512);
                // h2 half first (local data, streamed L2-warm B) while a1 lands
                #pragma unroll
                for (int ki = 0; ki < 24; ki++) {
                    bf16x8 b0 = *(const bf16x8*)(Bp0 + (ki + 24) * 32);
                    bf16x8 b1 = *(const bf16x8*)(Bp1 + (ki + 24) * 32);
                    acc0 = MFMA16(a2[ki], b0, acc0);
                    acc1 = MFMA16(a2[ki], b1, acc1);
                }
                // h1 half: pinned B, a1 landed by now
                #pragma unroll
                for (int ki = 0; ki < 24; ki++) {
                    acc0 = MFMA16(a1[ki], Bw0[ki], acc0);
                    acc1 = MFMA16(a1[ki], Bw1[ki], acc1);
                }
            } else {
                bf16x8 a1[24];
                #pragma unroll
                for (int ki = 0; ki < 24; ki++)
                    a1[ki] = *(const bf16x8*)(h1r + ki * 512);
                #pragma unroll
                for (int ki = 0; ki < 24; ki++) {
                    acc0 = MFMA16(a1[ki], Bw0[ki], acc0);
                    acc1 = MFMA16(a1[ki], Bw1[ki], acc1);
                }
            }
            f32x4 pacc0, pacc1;
            #pragma unroll
            for (int j = 0; j < 4; j++) {
                pacc0[j] = __shfl_xor(acc0[j], 8);
                pacc1[j] = __shfl_xor(acc1[j], 8);
            }
            if (lowhalf) {
                #pragma unroll
                for (int j = 0; j < 4; j++) {
                    int row = m0 + q * 4 + j;
                    float pi = acc0[j]  + bi;
                    float pf = pacc0[j] + bff;
                    float pg = acc1[j]  + bg;
                    float po = pacc1[j] + bo;
                    float cn = fast_sigm(pf) * creg[j] + fast_sigm(pi) * fast_tanh(pg);
                    float hn = fast_sigm(po) * fast_tanh(cn);
                    creg[j] = cn;
                    ldsb[wave][q * 4 + j][lane & 7] = f2bf(hn);
                    if (t == T_ - 1) hf32[(size_t)row * H_ + ecol] = hn;
                }
            }
            unsigned v = ((const unsigned*)&ldsb[wave][0][0])[lane];
            // PLAIN store: write-through L1 lands in local XCD L2 (local ring)
            *(unsigned*)(h2loc + ((size_t)t * 4 + g) * GSLOT_ + stoff_e) = v;
            asm volatile("s_waitcnt vmcnt(0)" ::: "memory");
            __syncthreads();
            if (tid == 0)
                st_llc_u32((unsigned*)&fself[role], (unsigned)s);
        }
        if (xcd == 7 && role == 0 && tid == 0) st_llc_u32((unsigned*)done, 1u);
    }
}

// ---------------- head ----------------
__global__ __launch_bounds__(256) void head_kernel(
    const float* __restrict__ hlast,
    const float* __restrict__ W1, const float* __restrict__ b1,
    const float* __restrict__ W2, const float* __restrict__ b2,
    float* __restrict__ out)
{
    __shared__ float hs[H_];
    __shared__ float partial[4];
    int b = blockIdx.x;
    int tid = threadIdx.x;
    for (int j = tid; j < H_; j += 256) hs[j] = hlast[(size_t)b * H_ + j];
    __syncthreads();
    float z = 0.f;
    const float* w = W1 + (size_t)tid * H_;
    for (int j = 0; j < H_; j++) z += hs[j] * w[j];
    z += b1[tid];
    z = z / (1.0f + fabsf(z));
    float p = z * W2[tid];
    #pragma unroll
    for (int off = 32; off > 0; off >>= 1) p += __shfl_down(p, off, 64);
    if ((tid & 63) == 0) partial[tid >> 6] = p;
    __syncthreads();
    if (tid == 0) {
        float s = partial[0] + partial[1] + partial[2] + partial[3];
        out[b] = (s + b2[0]) * 70.0f;
    }
}

extern "C" void kernel_launch(void* const* d_in, const int* in_sizes, int n_in,
                              void* d_out, int out_size, void* d_ws, size_t ws_size,
                              hipStream_t stream) {
    const float* x    = (const float*)d_in[0];
    const float* Wih0 = (const float*)d_in[1];
    const float* Whh0 = (const float*)d_in[2];
    const float* bih0 = (const float*)d_in[3];
    const float* bhh0 = (const float*)d_in[4];
    const float* Wih1 = (const float*)d_in[5];
    const float* Whh1 = (const float*)d_in[6];
    const float* bih1 = (const float*)d_in[7];
    const float* bhh1 = (const float*)d_in[8];
    const float* W1   = (const float*)d_in[9];
    const float* b1   = (const float*)d_in[10];
    const float* W2   = (const float*)d_in[11];
    const float* b2   = (const float*)d_in[12];
    float* out = (float*)d_out;

    const size_t RING = (size_t)T_ * 4 * GSLOT_ * 2;   // 24 MB each

    char* w = (char*)d_ws;
    int* ctrs = (int*)w;                          w += 65536;
    unsigned short* h1x   = (unsigned short*)w;   w += RING;
    unsigned short* h2loc = (unsigned short*)w;   w += RING;
    unsigned short* xsT   = (unsigned short*)w;   w += (size_t)B_ * T_ * IN_ * 2;
    unsigned short* W0cat = (unsigned short*)w;   w += (size_t)G_ * K0_ * 2;
    unsigned short* W1cat = (unsigned short*)w;   w += (size_t)G_ * K1_ * 2;
    float* bias0 = (float*)w;                     w += G_ * 4;
    float* bias1 = (float*)w;                     w += G_ * 4;
    float* hf32  = (float*)w;                     w += (size_t)B_ * H_ * 4;

    prep_kernel<<<1024, 256, 0, stream>>>(x, Wih0, Whh0, bih0, bhh0,
                                          Wih1, Whh1, bih1, bhh1,
                                          xsT, W0cat, W1cat, bias0, bias1, ctrs);
    lstm_persistent<<<NWGT, 256, 0, stream>>>(xsT, W0cat, W1cat, bias0, bias1,
                                              h1x, h2loc, hf32, ctrs);
    head_kernel<<<B_, 256, 0, stream>>>(hf32, W1, b1, W2, b2, out);
}

// Round 7
// 2955.400 us; speedup vs baseline: 1.1923x; 1.1923x over previous
//
#include <hip/hip_runtime.h>
#include <hip/hip_bf16.h>

// LSTM_Net round 17: XCD domains + weights that FIT (VGPR + LDS, zero stream).
// r16 post-mortem: domains worked (passed; XCC grab + plain local rings
// validated) but FETCH 282MB->1.84GB: each L1 XCD covered all 96 col-blocks
// so streamed h2-half weights = 4.5MB/XCD > 4MB L2 -> thrashed every step.
// Also ldspad was DCE'd (write-only LDS), and a1-first issue order forced
// vmcnt-FIFO stalls. r17:
//   - L1 per wave: pin 60 weight frags in VGPR (h1-half 48 + h2-half ki0..5),
//     stage remaining 36 frags in LDS ONCE (4 waves x 36KB = 144KB static).
//     LDS reads use lgkmcnt -> immune to vmcnt FIFO. Streamed L2 weights: 0.
//     144KB static LDS also replaces the pad (can't DCE): 1 WG/CU for real.
//   - L0: all 52 frags pinned (r16, worked).
//   - h1 dual-store: plain h1loc (local self-recurrence) + sc1 h1x (cross
//     L0->L1 handoff, feed-forward). h2loc plain/local (r16-validated).
//   - FIFO-correct order: issue a2(local) then a1(cross); compute h2-half
//     (pinned+LDS B) while a1 flies; then h1-half (pinned B).
//   - Flags: r16 verbatim (sc1 store + AGENT_LD poll; fself local set,
//     fx cross set). Still MALL -- next target if data-side wins.
// ctrs (ints): [0..7] role ctrs, fself[xcd]=ctrs[256+xcd*64+..24),
// fx[g]=ctrs[1024+g*64+..24), [2048] done.

#define B_  64
#define T_  256
#define IN_ 64
#define H_  768
#define G_  3072   // 4*H
#define K0_ 832    // IN_ + H_
#define K1_ 1536   // 2*H_
#define NWGT 256
#define GSLOT_ 12288   // per (t,group) ring slot elems = 96cbw * 16rows * 8cols

typedef __bf16 bf16_t;
typedef bf16_t bf16x8 __attribute__((ext_vector_type(8)));
typedef float  f32x4  __attribute__((ext_vector_type(4)));

__device__ __forceinline__ unsigned short f2bf(float f) {
    union { float f; unsigned u; } v; v.f = f;
    unsigned r = v.u + 0x7FFFu + ((v.u >> 16) & 1u);
    return (unsigned short)(r >> 16);
}
__device__ __forceinline__ float fast_sigm(float x) {
    float e = __builtin_amdgcn_exp2f(-1.44269504f * x);
    return __builtin_amdgcn_rcpf(1.0f + e);
}
__device__ __forceinline__ float fast_tanh(float x) {
    float e = __builtin_amdgcn_exp2f(2.88539008f * x);
    return (e - 1.0f) * __builtin_amdgcn_rcpf(e + 1.0f);
}
__device__ __forceinline__ void st_llc_u32(unsigned* p, unsigned v) {
    asm volatile("global_store_dword %0, %1, off sc1" :: "v"(p), "v"(v) : "memory");
}
#define MFMA16(a, b, c) __builtin_amdgcn_mfma_f32_16x16x32_bf16((a), (b), (c), 0, 0, 0)
#define AGENT_LD(p) __hip_atomic_load((p), __ATOMIC_RELAXED, __HIP_MEMORY_SCOPE_AGENT)
#define PIN8(v) asm volatile("" : "+v"(v))

// ---------------- prep ----------------
__global__ __launch_bounds__(256) void prep_kernel(
    const float* __restrict__ x,
    const float* __restrict__ Wih0, const float* __restrict__ Whh0,
    const float* __restrict__ bih0, const float* __restrict__ bhh0,
    const float* __restrict__ Wih1, const float* __restrict__ Whh1,
    const float* __restrict__ bih1, const float* __restrict__ bhh1,
    unsigned short* __restrict__ xsT,    // [T][B][64]
    unsigned short* __restrict__ W0cat,  // [3072][832]
    unsigned short* __restrict__ W1cat,  // [3072][1536]
    float* __restrict__ bias0, float* __restrict__ bias1,
    int* __restrict__ ctrs)              // [16384]
{
    int i = blockIdx.x * blockDim.x + threadIdx.x;
    int stride = gridDim.x * blockDim.x;
    for (int j = i; j < B_ * T_ * IN_; j += stride) {
        int b = j >> 14;
        int t = (j >> 6) & (T_ - 1);
        int k = j & (IN_ - 1);
        xsT[(((size_t)t * B_) + b) * IN_ + k] = f2bf(x[j] * (1.0f / 1.5f));
    }
    for (int j = i; j < G_ * IN_; j += stride) {
        int r = j >> 6; int k = j & 63;
        W0cat[(size_t)r * K0_ + k] = f2bf(Wih0[j]);
    }
    for (int j = i; j < G_ * H_; j += stride) {
        int r = j / H_; int k = j - r * H_;
        W0cat[(size_t)r * K0_ + IN_ + k] = f2bf(Whh0[j]);
        W1cat[(size_t)r * K1_ + k]       = f2bf(Wih1[j]);
        W1cat[(size_t)r * K1_ + H_ + k]  = f2bf(Whh1[j]);
    }
    for (int j = i; j < G_; j += stride) {
        bias0[j] = bih0[j] + bhh0[j];
        bias1[j] = bih1[j] + bhh1[j];
    }
    for (int j = i; j < 16384; j += stride) ctrs[j] = 0;
}

// ---------------- persistent XCD-domain recurrence ----------------
__global__ __launch_bounds__(256, 1) void lstm_persistent(
    const unsigned short* __restrict__ xsT,
    const unsigned short* __restrict__ W0cat,
    const unsigned short* __restrict__ W1cat,
    const float* __restrict__ bias0, const float* __restrict__ bias1,
    unsigned short* __restrict__ h1loc,  // [T][4g][96cbw][16][8] plain/local
    unsigned short* __restrict__ h1x,    // [T][4g][96cbw][16][8] sc1/cross
    unsigned short* __restrict__ h2loc,  // [T][4g][96cbw][16][8] plain/local
    float* __restrict__ hf32,            // [B][H] fp32 (t = T-1)
    int* __restrict__ ctrs)
{
    __shared__ unsigned short ldsb[4][16][8];
    // 144KB weight stage (L1 waves: 36 frags x 1KB each). Also forces
    // 1 WG/CU (145KB static LDS) -- replaces the DCE-prone pad.
    __shared__ char wstage[4][36][1024];
    __shared__ int role_s;

    const int tid  = threadIdx.x;
    const int lane = tid & 63;
    const int wave = tid >> 6;

    int xcd;
    asm volatile("s_getreg_b32 %0, hwreg(HW_REG_XCC_ID)" : "=s"(xcd));
    xcd &= 7;

    if (tid == 0) role_s = atomicAdd(&ctrs[xcd], 1);
    __syncthreads();
    const int role = role_s;

    int* done = &ctrs[2048];

    // ---------- heater roles: pin GFX clock; poll dedicated done line ------
    if (role >= 24) {
        float a = 1.0f + (float)tid * 1e-7f;
        const float bm = 1.0000001f, cm = 1e-9f;
        for (;;) {
            for (int i = 0; i < 2048; i++)
                a = __builtin_fmaf(a, bm, cm);
            asm volatile("" : "+v"(a));
            int d = 0;
            if (lane == 0) d = AGENT_LD(done);
            d = __builtin_amdgcn_readfirstlane(d);
            if (d != 0) break;
        }
        return;
    }

    const int l  = xcd & 1;          // layer handled by this XCD
    const int g  = xcd >> 1;         // batch group (16 rows)
    const int m0 = g * 16;           // group's batch-row base
    const int cbw = role * 4 + wave; // H-col block 0..95 (8 cols each)
    const int c0  = cbw * 8;
    const int frow = lane & 15;
    const int q    = lane >> 4;
    const int kof  = q * 8;

    int fidx = lane; if (fidx >= 48) fidx -= 48; if (fidx >= 24) fidx -= 24;
    int* fself = &ctrs[256 + xcd * 64];   // my domain's 24 self flags
    int* fx    = &ctrs[1024 + g * 64];    // cross-die h1 flags for group g

    const unsigned short* Wc = l ? W1cat : W0cat;
    const int Kc = l ? K1_ : K0_;
    int q0 = frow >> 3, col0 = c0 + (frow & 7);
    const unsigned short* Bp0 = Wc + (size_t)(q0 * H_ + col0) * Kc + kof;       // gates i,f
    const unsigned short* Bp1 = Wc + (size_t)((2 + q0) * H_ + col0) * Kc + kof; // gates g,o

    const float* bias = l ? bias1 : bias0;
    const bool lowhalf = (lane & 15) < 8;
    const int ecol = c0 + (lane & 7);
    float bi = 0.f, bff = 0.f, bg = 0.f, bo = 0.f;
    if (lowhalf) {
        bi  = bias[0 * H_ + ecol];
        bff = bias[1 * H_ + ecol];
        bg  = bias[2 * H_ + ecol];
        bo  = bias[3 * H_ + ecol];
    }
    float creg[4] = {0.f, 0.f, 0.f, 0.f};

    const size_t aoff = (size_t)q * 128 + (size_t)frow * 8;
    const size_t stoff_e = (size_t)cbw * 128 + (size_t)(lane >> 2) * 8
                         + (size_t)(lane & 3) * 2;

    if (l == 0) {
        // ------------- layer 0 domain: superstep s computes h1[s] -----------
        bf16x8 Bw0[26], Bw1[26];
        #pragma unroll
        for (int k = 0; k < 26; k++) {
            Bw0[k] = *(const bf16x8*)(Bp0 + k * 32);
            Bw1[k] = *(const bf16x8*)(Bp1 + k * 32);
        }
        #pragma unroll
        for (int k = 0; k < 26; k++) { PIN8(Bw0[k]); PIN8(Bw1[k]); }
        for (int s = 0; s < T_; ++s) {
            f32x4 acc0 = {0.f, 0.f, 0.f, 0.f};
            f32x4 acc1 = {0.f, 0.f, 0.f, 0.f};
            {
                const unsigned short* xsp =
                    xsT + ((size_t)s * B_ + m0 + frow) * IN_ + kof;
                bf16x8 ax0 = *(const bf16x8*)(xsp);
                bf16x8 ax1 = *(const bf16x8*)(xsp + 32);
                acc0 = MFMA16(ax0, Bw0[0], acc0);
                acc1 = MFMA16(ax0, Bw1[0], acc1);
                acc0 = MFMA16(ax1, Bw0[1], acc0);
                acc1 = MFMA16(ax1, Bw1[1], acc1);
            }
            if (s > 0) {
                if (wave == 0) {   // all 24 self flags >= s
                    const int* fp = &fself[fidx];
                    for (;;) {
                        int v = AGENT_LD(fp);
                        if (__all(v >= s)) break;
                        __builtin_amdgcn_s_sleep(1);
                    }
                }
                __syncthreads();
                const unsigned short* hr =
                    h1loc + ((size_t)(s - 1) * 4 + g) * GSLOT_ + aoff;
                bf16x8 a[24];
                #pragma unroll
                for (int kj = 0; kj < 24; kj++)
                    a[kj] = *(const bf16x8*)(hr + kj * 512);
                #pragma unroll
                for (int kj = 0; kj < 24; kj++) {
                    acc0 = MFMA16(a[kj], Bw0[kj + 2], acc0);
                    acc1 = MFMA16(a[kj], Bw1[kj + 2], acc1);
                }
            }
            f32x4 pacc0, pacc1;
            #pragma unroll
            for (int j = 0; j < 4; j++) {
                pacc0[j] = __shfl_xor(acc0[j], 8);
                pacc1[j] = __shfl_xor(acc1[j], 8);
            }
            if (lowhalf) {
                #pragma unroll
                for (int j = 0; j < 4; j++) {
                    float pi = acc0[j]  + bi;
                    float pf = pacc0[j] + bff;
                    float pg = acc1[j]  + bg;
                    float po = pacc1[j] + bo;
                    float cn = fast_sigm(pf) * creg[j] + fast_sigm(pi) * fast_tanh(pg);
                    float hn = fast_sigm(po) * fast_tanh(cn);
                    creg[j] = cn;
                    ldsb[wave][q * 4 + j][lane & 7] = f2bf(hn);
                }
            }
            unsigned v = ((const unsigned*)&ldsb[wave][0][0])[lane];
            {
                size_t so = ((size_t)s * 4 + g) * GSLOT_ + stoff_e;
                *(unsigned*)(h1loc + so) = v;            // local copy (plain)
                st_llc_u32((unsigned*)(h1x + so), v);    // cross copy (sc1)
            }
            asm volatile("s_waitcnt vmcnt(0)" ::: "memory");
            __syncthreads();
            if (tid == 0) {
                st_llc_u32((unsigned*)&fself[role], (unsigned)(s + 1));
                st_llc_u32((unsigned*)&fx[role],    (unsigned)(s + 1));
            }
        }
    } else {
        // ------------- layer 1 domain: superstep s computes h2[s-1] ---------
        // Weights: pin h1-half 48 frags + h2-half ki0..5 (12 frags) = 240 VGPR;
        // stage h2-half ki6..23 (36 frags, 36KB) in this wave's LDS quadrant.
        bf16x8 Bw0[24], Bw1[24];   // h1-half
        #pragma unroll
        for (int k = 0; k < 24; k++) {
            Bw0[k] = *(const bf16x8*)(Bp0 + k * 32);
            Bw1[k] = *(const bf16x8*)(Bp1 + k * 32);
        }
        bf16x8 Cw0[6], Cw1[6];     // h2-half ki 0..5
        #pragma unroll
        for (int k = 0; k < 6; k++) {
            Cw0[k] = *(const bf16x8*)(Bp0 + (24 + k) * 32);
            Cw1[k] = *(const bf16x8*)(Bp1 + (24 + k) * 32);
        }
        #pragma unroll
        for (int k = 0; k < 24; k++) { PIN8(Bw0[k]); PIN8(Bw1[k]); }
        #pragma unroll
        for (int k = 0; k < 6; k++)  { PIN8(Cw0[k]); PIN8(Cw1[k]); }
        #pragma unroll
        for (int f = 0; f < 18; f++) {   // stage ki = 6+f
            bf16x8 b0 = *(const bf16x8*)(Bp0 + (30 + f) * 32);
            bf16x8 b1 = *(const bf16x8*)(Bp1 + (30 + f) * 32);
            *(bf16x8*)&wstage[wave][2 * f][lane * 16]     = b0;
            *(bf16x8*)&wstage[wave][2 * f + 1][lane * 16] = b1;
        }
        for (int s = 1; s <= T_; ++s) {
            const int t = s - 1;
            if (wave == 0) {   // h1[t] ready cross-die: fx >= t+1 = s
                const int* fp = &fx[fidx];
                for (;;) {
                    int v = AGENT_LD(fp);
                    if (__all(v >= s)) break;
                    __builtin_amdgcn_s_sleep(1);
                }
            }
            if (wave == 1 && t > 0) {   // h2[t-1] ready local: fself >= t
                const int* fp = &fself[fidx];
                for (;;) {
                    int v = AGENT_LD(fp);
                    if (__all(v >= t)) break;
                    __builtin_amdgcn_s_sleep(1);
                }
            }
            __syncthreads();
            f32x4 acc0 = {0.f, 0.f, 0.f, 0.f};
            f32x4 acc1 = {0.f, 0.f, 0.f, 0.f};
            const unsigned short* h1r = h1x + ((size_t)t * 4 + g) * GSLOT_ + aoff;
            if (t > 0) {
                const unsigned short* h2r =
                    h2loc + ((size_t)(t - 1) * 4 + g) * GSLOT_ + aoff;
                // FIFO order: a2 (local, fast) first, then a1 (cross, slow)
                bf16x8 a2[24];
                #pragma unroll
                for (int ki = 0; ki < 24; ki++)
                    a2[ki] = *(const bf16x8*)(h2r + ki * 512);
                bf16x8 a1[24];
                #pragma unroll
                for (int ki = 0; ki < 24; ki++)
                    a1[ki] = *(const bf16x8*)(h1r + ki * 512);
                // h2-half: ki0..5 pinned, ki6..23 B from LDS (lgkmcnt,
                // doesn't touch vmcnt FIFO) -- runs while a1 flies
                #pragma unroll
                for (int ki = 0; ki < 6; ki++) {
                    acc0 = MFMA16(a2[ki], Cw0[ki], acc0);
                    acc1 = MFMA16(a2[ki], Cw1[ki], acc1);
                }
                #pragma unroll
                for (int ki = 6; ki < 24; ki++) {
                    int f = ki - 6;
                    bf16x8 b0 = *(const bf16x8*)&wstage[wave][2 * f][lane * 16];
                    bf16x8 b1 = *(const bf16x8*)&wstage[wave][2 * f + 1][lane * 16];
                    acc0 = MFMA16(a2[ki], b0, acc0);
                    acc1 = MFMA16(a2[ki], b1, acc1);
                }
                // h1-half: pinned B, a1 landed by now
                #pragma unroll
                for (int ki = 0; ki < 24; ki++) {
                    acc0 = MFMA16(a1[ki], Bw0[ki], acc0);
                    acc1 = MFMA16(a1[ki], Bw1[ki], acc1);
                }
            } else {
                bf16x8 a1[24];
                #pragma unroll
                for (int ki = 0; ki < 24; ki++)
                    a1[ki] = *(const bf16x8*)(h1r + ki * 512);
                #pragma unroll
                for (int ki = 0; ki < 24; ki++) {
                    acc0 = MFMA16(a1[ki], Bw0[ki], acc0);
                    acc1 = MFMA16(a1[ki], Bw1[ki], acc1);
                }
            }
            f32x4 pacc0, pacc1;
            #pragma unroll
            for (int j = 0; j < 4; j++) {
                pacc0[j] = __shfl_xor(acc0[j], 8);
                pacc1[j] = __shfl_xor(acc1[j], 8);
            }
            if (lowhalf) {
                #pragma unroll
                for (int j = 0; j < 4; j++) {
                    int row = m0 + q * 4 + j;
                    float pi = acc0[j]  + bi;
                    float pf = pacc0[j] + bff;
                    float pg = acc1[j]  + bg;
                    float po = pacc1[j] + bo;
                    float cn = fast_sigm(pf) * creg[j] + fast_sigm(pi) * fast_tanh(pg);
                    float hn = fast_sigm(po) * fast_tanh(cn);
                    creg[j] = cn;
                    ldsb[wave][q * 4 + j][lane & 7] = f2bf(hn);
                    if (t == T_ - 1) hf32[(size_t)row * H_ + ecol] = hn;
                }
            }
            unsigned v = ((const unsigned*)&ldsb[wave][0][0])[lane];
            *(unsigned*)(h2loc + ((size_t)t * 4 + g) * GSLOT_ + stoff_e) = v;
            asm volatile("s_waitcnt vmcnt(0)" ::: "memory");
            __syncthreads();
            if (tid == 0)
                st_llc_u32((unsigned*)&fself[role], (unsigned)s);
        }
        if (xcd == 7 && role == 0 && tid == 0) st_llc_u32((unsigned*)done, 1u);
    }
}

// ---------------- head ----------------
__global__ __launch_bounds__(256) void head_kernel(
    const float* __restrict__ hlast,
    const float* __restrict__ W1, const float* __restrict__ b1,
    const float* __restrict__ W2, const float* __restrict__ b2,
    float* __restrict__ out)
{
    __shared__ float hs[H_];
    __shared__ float partial[4];
    int b = blockIdx.x;
    int tid = threadIdx.x;
    for (int j = tid; j < H_; j += 256) hs[j] = hlast[(size_t)b * H_ + j];
    __syncthreads();
    float z = 0.f;
    const float* w = W1 + (size_t)tid * H_;
    for (int j = 0; j < H_; j++) z += hs[j] * w[j];
    z += b1[tid];
    z = z / (1.0f + fabsf(z));
    float p = z * W2[tid];
    #pragma unroll
    for (int off = 32; off > 0; off >>= 1) p += __shfl_down(p, off, 64);
    if ((tid & 63) == 0) partial[tid >> 6] = p;
    __syncthreads();
    if (tid == 0) {
        float s = partial[0] + partial[1] + partial[2] + partial[3];
        out[b] = (s + b2[0]) * 70.0f;
    }
}

extern "C" void kernel_launch(void* const* d_in, const int* in_sizes, int n_in,
                              void* d_out, int out_size, void* d_ws, size_t ws_size,
                              hipStream_t stream) {
    const float* x    = (const float*)d_in[0];
    const float* Wih0 = (const float*)d_in[1];
    const float* Whh0 = (const float*)d_in[2];
    const float* bih0 = (const float*)d_in[3];
    const float* bhh0 = (const float*)d_in[4];
    const float* Wih1 = (const float*)d_in[5];
    const float* Whh1 = (const float*)d_in[6];
    const float* bih1 = (const float*)d_in[7];
    const float* bhh1 = (const float*)d_in[8];
    const float* W1   = (const float*)d_in[9];
    const float* b1   = (const float*)d_in[10];
    const float* W2   = (const float*)d_in[11];
    const float* b2   = (const float*)d_in[12];
    float* out = (float*)d_out;

    const size_t RING = (size_t)T_ * 4 * GSLOT_ * 2;   // 24 MB each

    char* w = (char*)d_ws;
    int* ctrs = (int*)w;                          w += 65536;
    unsigned short* h1loc = (unsigned short*)w;   w += RING;
    unsigned short* h1x   = (unsigned short*)w;   w += RING;
    unsigned short* h2loc = (unsigned short*)w;   w += RING;
    unsigned short* xsT   = (unsigned short*)w;   w += (size_t)B_ * T_ * IN_ * 2;
    unsigned short* W0cat = (unsigned short*)w;   w += (size_t)G_ * K0_ * 2;
    unsigned short* W1cat = (unsigned short*)w;   w += (size_t)G_ * K1_ * 2;
    float* bias0 = (float*)w;                     w += G_ * 4;
    float* bias1 = (float*)w;                     w += G_ * 4;
    float* hf32  = (float*)w;                     w += (size_t)B_ * H_ * 4;

    prep_kernel<<<1024, 256, 0, stream>>>(x, Wih0, Whh0, bih0, bhh0,
                                          Wih1, Whh1, bih1, bhh1,
                                          xsT, W0cat, W1cat, bias0, bias1, ctrs);
    lstm_persistent<<<NWGT, 256, 0, stream>>>(xsT, W0cat, W1cat, bias0, bias1,
                                              h1loc, h1x, h2loc, hf32, ctrs);
    head_kernel<<<B_, 256, 0, stream>>>(hf32, W1, b1, W2, b2, out);
}

// Round 9
// 1733.600 us; speedup vs baseline: 2.0326x; 1.7048x over previous
//
#include <hip/hip_runtime.h>
#include <hip/hip_bf16.h>

// LSTM_Net round 19: r17 skeleton VERBATIM + "+a" (AGPR) weight pins.
// r18 post-mortem: 2nd container death; both deaths (r15, r18) contained
// sc0 poll loads, both clean runs (r16, r17) did not -> sc0 loads banned.
// "+a" pins remain untested -> r19 isolates exactly that one variable on
// the proven r17 structure (ran clean; FETCH 282->67MB proved locality;
// VGPR=256 peg + accvgpr churn convicted "+v" pins of the 3040us time).
//   - PIN8A "+a": weights in a0..a239, MFMA reads B straight from AGPRs
//     (ISA 10: A/B from VGPR or AGPR). Arch VGPRs freed for a1/a2 + epilogue.
//     Budget @1 wave/SIMD: L0 208a+~150v, L1 240a+~240v, both < 512 unified.
//   - ALL sync = r17 verbatim: sc1 stores + AGENT_LD polls, fself/fx flags,
//     plain-store local rings, LDS weight stage (144KB, forces 1 WG/CU),
//     XCC_ID role grab, heaters.
// Pre-registered: fail -> "+a" convicted, revert to r14 skeleton; >=2900 ->
// regalloc wasn't r17's bottleneck; 1600-2300 -> domain structure vindicated.
// ctrs (ints): [0..7] roles, fself[xcd]=256+xcd*64 (+24), fx[g]=1024+g*64,
// [2048] done.

#define B_  64
#define T_  256
#define IN_ 64
#define H_  768
#define G_  3072   // 4*H
#define K0_ 832    // IN_ + H_
#define K1_ 1536   // 2*H_
#define NWGT 256
#define GSLOT_ 12288   // per (t,group) ring slot elems = 96cbw * 16rows * 8cols

typedef __bf16 bf16_t;
typedef bf16_t bf16x8 __attribute__((ext_vector_type(8)));
typedef float  f32x4  __attribute__((ext_vector_type(4)));

__device__ __forceinline__ unsigned short f2bf(float f) {
    union { float f; unsigned u; } v; v.f = f;
    unsigned r = v.u + 0x7FFFu + ((v.u >> 16) & 1u);
    return (unsigned short)(r >> 16);
}
__device__ __forceinline__ float fast_sigm(float x) {
    float e = __builtin_amdgcn_exp2f(-1.44269504f * x);
    return __builtin_amdgcn_rcpf(1.0f + e);
}
__device__ __forceinline__ float fast_tanh(float x) {
    float e = __builtin_amdgcn_exp2f(2.88539008f * x);
    return (e - 1.0f) * __builtin_amdgcn_rcpf(e + 1.0f);
}
__device__ __forceinline__ void st_llc_u32(unsigned* p, unsigned v) {
    asm volatile("global_store_dword %0, %1, off sc1" :: "v"(p), "v"(v) : "memory");
}
#define MFMA16(a, b, c) __builtin_amdgcn_mfma_f32_16x16x32_bf16((a), (b), (c), 0, 0, 0)
#define AGENT_LD(p) __hip_atomic_load((p), __ATOMIC_RELAXED, __HIP_MEMORY_SCOPE_AGENT)
// Pin into AGPRs: MFMA reads B directly from a-regs; arch VGPRs stay free.
#define PIN8A(v) asm volatile("" : "+a"(v))

// ---------------- prep ----------------
__global__ __launch_bounds__(256) void prep_kernel(
    const float* __restrict__ x,
    const float* __restrict__ Wih0, const float* __restrict__ Whh0,
    const float* __restrict__ bih0, const float* __restrict__ bhh0,
    const float* __restrict__ Wih1, const float* __restrict__ Whh1,
    const float* __restrict__ bih1, const float* __restrict__ bhh1,
    unsigned short* __restrict__ xsT,    // [T][B][64]
    unsigned short* __restrict__ W0cat,  // [3072][832]
    unsigned short* __restrict__ W1cat,  // [3072][1536]
    float* __restrict__ bias0, float* __restrict__ bias1,
    int* __restrict__ ctrs)              // [16384]
{
    int i = blockIdx.x * blockDim.x + threadIdx.x;
    int stride = gridDim.x * blockDim.x;
    for (int j = i; j < B_ * T_ * IN_; j += stride) {
        int b = j >> 14;
        int t = (j >> 6) & (T_ - 1);
        int k = j & (IN_ - 1);
        xsT[(((size_t)t * B_) + b) * IN_ + k] = f2bf(x[j] * (1.0f / 1.5f));
    }
    for (int j = i; j < G_ * IN_; j += stride) {
        int r = j >> 6; int k = j & 63;
        W0cat[(size_t)r * K0_ + k] = f2bf(Wih0[j]);
    }
    for (int j = i; j < G_ * H_; j += stride) {
        int r = j / H_; int k = j - r * H_;
        W0cat[(size_t)r * K0_ + IN_ + k] = f2bf(Whh0[j]);
        W1cat[(size_t)r * K1_ + k]       = f2bf(Wih1[j]);
        W1cat[(size_t)r * K1_ + H_ + k]  = f2bf(Whh1[j]);
    }
    for (int j = i; j < G_; j += stride) {
        bias0[j] = bih0[j] + bhh0[j];
        bias1[j] = bih1[j] + bhh1[j];
    }
    for (int j = i; j < 16384; j += stride) ctrs[j] = 0;
}

// ---------------- persistent XCD-domain recurrence ----------------
__global__ __launch_bounds__(256, 1) void lstm_persistent(
    const unsigned short* __restrict__ xsT,
    const unsigned short* __restrict__ W0cat,
    const unsigned short* __restrict__ W1cat,
    const float* __restrict__ bias0, const float* __restrict__ bias1,
    unsigned short* __restrict__ h1loc,  // [T][4g][96cbw][16][8] plain/local
    unsigned short* __restrict__ h1x,    // [T][4g][96cbw][16][8] sc1/cross
    unsigned short* __restrict__ h2loc,  // [T][4g][96cbw][16][8] plain/local
    float* __restrict__ hf32,            // [B][H] fp32 (t = T-1)
    int* __restrict__ ctrs)
{
    __shared__ unsigned short ldsb[4][16][8];
    // 144KB weight stage (L1 waves: 36 frags x 1KB each). Also forces
    // 1 WG/CU (145KB static LDS).
    __shared__ char wstage[4][36][1024];
    __shared__ int role_s;

    const int tid  = threadIdx.x;
    const int lane = tid & 63;
    const int wave = tid >> 6;

    int xcd;
    asm volatile("s_getreg_b32 %0, hwreg(HW_REG_XCC_ID)" : "=s"(xcd));
    xcd &= 7;

    if (tid == 0) role_s = atomicAdd(&ctrs[xcd], 1);
    __syncthreads();
    const int role = role_s;

    int* done = &ctrs[2048];

    // ---------- heater roles: pin GFX clock; poll dedicated done line ------
    if (role >= 24) {
        float a = 1.0f + (float)tid * 1e-7f;
        const float bm = 1.0000001f, cm = 1e-9f;
        for (;;) {
            for (int i = 0; i < 2048; i++)
                a = __builtin_fmaf(a, bm, cm);
            asm volatile("" : "+v"(a));
            int d = 0;
            if (lane == 0) d = AGENT_LD(done);
            d = __builtin_amdgcn_readfirstlane(d);
            if (d != 0) break;
        }
        return;
    }

    const int l  = xcd & 1;          // layer handled by this XCD
    const int g  = xcd >> 1;         // batch group (16 rows)
    const int m0 = g * 16;           // group's batch-row base
    const int cbw = role * 4 + wave; // H-col block 0..95 (8 cols each)
    const int c0  = cbw * 8;
    const int frow = lane & 15;
    const int q    = lane >> 4;
    const int kof  = q * 8;

    int fidx = lane; if (fidx >= 48) fidx -= 48; if (fidx >= 24) fidx -= 24;
    int* fself = &ctrs[256 + xcd * 64];   // my domain's 24 self flags
    int* fx    = &ctrs[1024 + g * 64];    // cross-die h1 flags for group g

    const unsigned short* Wc = l ? W1cat : W0cat;
    const int Kc = l ? K1_ : K0_;
    int q0 = frow >> 3, col0 = c0 + (frow & 7);
    const unsigned short* Bp0 = Wc + (size_t)(q0 * H_ + col0) * Kc + kof;       // gates i,f
    const unsigned short* Bp1 = Wc + (size_t)((2 + q0) * H_ + col0) * Kc + kof; // gates g,o

    const float* bias = l ? bias1 : bias0;
    const bool lowhalf = (lane & 15) < 8;
    const int ecol = c0 + (lane & 7);
    float bi = 0.f, bff = 0.f, bg = 0.f, bo = 0.f;
    if (lowhalf) {
        bi  = bias[0 * H_ + ecol];
        bff = bias[1 * H_ + ecol];
        bg  = bias[2 * H_ + ecol];
        bo  = bias[3 * H_ + ecol];
    }
    float creg[4] = {0.f, 0.f, 0.f, 0.f};

    const size_t aoff = (size_t)q * 128 + (size_t)frow * 8;
    const size_t stoff_e = (size_t)cbw * 128 + (size_t)(lane >> 2) * 8
                         + (size_t)(lane & 3) * 2;

    if (l == 0) {
        // ------------- layer 0 domain: superstep s computes h1[s] -----------
        bf16x8 Bw0[26], Bw1[26];
        #pragma unroll
        for (int k = 0; k < 26; k++) {
            Bw0[k] = *(const bf16x8*)(Bp0 + k * 32);
            Bw1[k] = *(const bf16x8*)(Bp1 + k * 32);
        }
        #pragma unroll
        for (int k = 0; k < 26; k++) { PIN8A(Bw0[k]); PIN8A(Bw1[k]); }
        for (int s = 0; s < T_; ++s) {
            f32x4 acc0 = {0.f, 0.f, 0.f, 0.f};
            f32x4 acc1 = {0.f, 0.f, 0.f, 0.f};
            {
                const unsigned short* xsp =
                    xsT + ((size_t)s * B_ + m0 + frow) * IN_ + kof;
                bf16x8 ax0 = *(const bf16x8*)(xsp);
                bf16x8 ax1 = *(const bf16x8*)(xsp + 32);
                acc0 = MFMA16(ax0, Bw0[0], acc0);
                acc1 = MFMA16(ax0, Bw1[0], acc1);
                acc0 = MFMA16(ax1, Bw0[1], acc0);
                acc1 = MFMA16(ax1, Bw1[1], acc1);
            }
            if (s > 0) {
                if (wave == 0) {   // all 24 self flags >= s
                    const int* fp = &fself[fidx];
                    for (;;) {
                        int v = AGENT_LD(fp);
                        if (__all(v >= s)) break;
                        __builtin_amdgcn_s_sleep(1);
                    }
                }
                __syncthreads();
                const unsigned short* hr =
                    h1loc + ((size_t)(s - 1) * 4 + g) * GSLOT_ + aoff;
                bf16x8 a[24];
                #pragma unroll
                for (int kj = 0; kj < 24; kj++)
                    a[kj] = *(const bf16x8*)(hr + kj * 512);
                #pragma unroll
                for (int kj = 0; kj < 24; kj++) {
                    acc0 = MFMA16(a[kj], Bw0[kj + 2], acc0);
                    acc1 = MFMA16(a[kj], Bw1[kj + 2], acc1);
                }
            }
            f32x4 pacc0, pacc1;
            #pragma unroll
            for (int j = 0; j < 4; j++) {
                pacc0[j] = __shfl_xor(acc0[j], 8);
                pacc1[j] = __shfl_xor(acc1[j], 8);
            }
            if (lowhalf) {
                #pragma unroll
                for (int j = 0; j < 4; j++) {
                    float pi = acc0[j]  + bi;
                    float pf = pacc0[j] + bff;
                    float pg = acc1[j]  + bg;
                    float po = pacc1[j] + bo;
                    float cn = fast_sigm(pf) * creg[j] + fast_sigm(pi) * fast_tanh(pg);
                    float hn = fast_sigm(po) * fast_tanh(cn);
                    creg[j] = cn;
                    ldsb[wave][q * 4 + j][lane & 7] = f2bf(hn);
                }
            }
            unsigned v = ((const unsigned*)&ldsb[wave][0][0])[lane];
            {
                size_t so = ((size_t)s * 4 + g) * GSLOT_ + stoff_e;
                *(unsigned*)(h1loc + so) = v;            // local copy (plain)
                st_llc_u32((unsigned*)(h1x + so), v);    // cross copy (sc1)
            }
            asm volatile("s_waitcnt vmcnt(0)" ::: "memory");
            __syncthreads();
            if (tid == 0) {
                st_llc_u32((unsigned*)&fself[role], (unsigned)(s + 1));
                st_llc_u32((unsigned*)&fx[role],    (unsigned)(s + 1));
            }
        }
    } else {
        // ------------- layer 1 domain: superstep s computes h2[s-1] ---------
        // Weights: h1-half 48 frags + h2-half ki0..5 (12) pinned in AGPRs
        // (240 a-regs); h2-half ki6..23 (36 frags) staged in LDS.
        bf16x8 Bw0[24], Bw1[24];   // h1-half
        #pragma unroll
        for (int k = 0; k < 24; k++) {
            Bw0[k] = *(const bf16x8*)(Bp0 + k * 32);
            Bw1[k] = *(const bf16x8*)(Bp1 + k * 32);
        }
        bf16x8 Cw0[6], Cw1[6];     // h2-half ki 0..5
        #pragma unroll
        for (int k = 0; k < 6; k++) {
            Cw0[k] = *(const bf16x8*)(Bp0 + (24 + k) * 32);
            Cw1[k] = *(const bf16x8*)(Bp1 + (24 + k) * 32);
        }
        #pragma unroll
        for (int k = 0; k < 24; k++) { PIN8A(Bw0[k]); PIN8A(Bw1[k]); }
        #pragma unroll
        for (int k = 0; k < 6; k++)  { PIN8A(Cw0[k]); PIN8A(Cw1[k]); }
        #pragma unroll
        for (int f = 0; f < 18; f++) {   // stage ki = 6+f
            bf16x8 b0 = *(const bf16x8*)(Bp0 + (30 + f) * 32);
            bf16x8 b1 = *(const bf16x8*)(Bp1 + (30 + f) * 32);
            *(bf16x8*)&wstage[wave][2 * f][lane * 16]     = b0;
            *(bf16x8*)&wstage[wave][2 * f + 1][lane * 16] = b1;
        }
        for (int s = 1; s <= T_; ++s) {
            const int t = s - 1;
            if (wave == 0) {   // h1[t] ready cross-die: fx >= t+1 = s
                const int* fp = &fx[fidx];
                for (;;) {
                    int v = AGENT_LD(fp);
                    if (__all(v >= s)) break;
                    __builtin_amdgcn_s_sleep(1);
                }
            }
            if (wave == 1 && t > 0) {   // h2[t-1] ready local: fself >= t
                const int* fp = &fself[fidx];
                for (;;) {
                    int v = AGENT_LD(fp);
                    if (__all(v >= t)) break;
                    __builtin_amdgcn_s_sleep(1);
                }
            }
            __syncthreads();
            f32x4 acc0 = {0.f, 0.f, 0.f, 0.f};
            f32x4 acc1 = {0.f, 0.f, 0.f, 0.f};
            const unsigned short* h1r = h1x + ((size_t)t * 4 + g) * GSLOT_ + aoff;
            if (t > 0) {
                const unsigned short* h2r =
                    h2loc + ((size_t)(t - 1) * 4 + g) * GSLOT_ + aoff;
                // FIFO order: a2 (local, fast) first, then a1 (cross, slow)
                bf16x8 a2[24];
                #pragma unroll
                for (int ki = 0; ki < 24; ki++)
                    a2[ki] = *(const bf16x8*)(h2r + ki * 512);
                bf16x8 a1[24];
                #pragma unroll
                for (int ki = 0; ki < 24; ki++)
                    a1[ki] = *(const bf16x8*)(h1r + ki * 512);
                // h2-half: ki0..5 AGPR B, ki6..23 LDS B (lgkmcnt path,
                // immune to vmcnt FIFO) -- runs while a1 flies
                #pragma unroll
                for (int ki = 0; ki < 6; ki++) {
                    acc0 = MFMA16(a2[ki], Cw0[ki], acc0);
                    acc1 = MFMA16(a2[ki], Cw1[ki], acc1);
                }
                #pragma unroll
                for (int ki = 6; ki < 24; ki++) {
                    int f = ki - 6;
                    bf16x8 b0 = *(const bf16x8*)&wstage[wave][2 * f][lane * 16];
                    bf16x8 b1 = *(const bf16x8*)&wstage[wave][2 * f + 1][lane * 16];
                    acc0 = MFMA16(a2[ki], b0, acc0);
                    acc1 = MFMA16(a2[ki], b1, acc1);
                }
                // h1-half: AGPR B, a1 landed by now
                #pragma unroll
                for (int ki = 0; ki < 24; ki++) {
                    acc0 = MFMA16(a1[ki], Bw0[ki], acc0);
                    acc1 = MFMA16(a1[ki], Bw1[ki], acc1);
                }
            } else {
                bf16x8 a1[24];
                #pragma unroll
                for (int ki = 0; ki < 24; ki++)
                    a1[ki] = *(const bf16x8*)(h1r + ki * 512);
                #pragma unroll
                for (int ki = 0; ki < 24; ki++) {
                    acc0 = MFMA16(a1[ki], Bw0[ki], acc0);
                    acc1 = MFMA16(a1[ki], Bw1[ki], acc1);
                }
            }
            f32x4 pacc0, pacc1;
            #pragma unroll
            for (int j = 0; j < 4; j++) {
                pacc0[j] = __shfl_xor(acc0[j], 8);
                pacc1[j] = __shfl_xor(acc1[j], 8);
            }
            if (lowhalf) {
                #pragma unroll
                for (int j = 0; j < 4; j++) {
                    int row = m0 + q * 4 + j;
                    float pi = acc0[j]  + bi;
                    float pf = pacc0[j] + bff;
                    float pg = acc1[j]  + bg;
                    float po = pacc1[j] + bo;
                    float cn = fast_sigm(pf) * creg[j] + fast_sigm(pi) * fast_tanh(pg);
                    float hn = fast_sigm(po) * fast_tanh(cn);
                    creg[j] = cn;
                    ldsb[wave][q * 4 + j][lane & 7] = f2bf(hn);
                    if (t == T_ - 1) hf32[(size_t)row * H_ + ecol] = hn;
                }
            }
            unsigned v = ((const unsigned*)&ldsb[wave][0][0])[lane];
            *(unsigned*)(h2loc + ((size_t)t * 4 + g) * GSLOT_ + stoff_e) = v;
            asm volatile("s_waitcnt vmcnt(0)" ::: "memory");
            __syncthreads();
            if (tid == 0)
                st_llc_u32((unsigned*)&fself[role], (unsigned)s);
        }
        if (xcd == 7 && role == 0 && tid == 0) st_llc_u32((unsigned*)done, 1u);
    }
}

// ---------------- head ----------------
__global__ __launch_bounds__(256) void head_kernel(
    const float* __restrict__ hlast,
    const float* __restrict__ W1, const float* __restrict__ b1,
    const float* __restrict__ W2, const float* __restrict__ b2,
    float* __restrict__ out)
{
    __shared__ float hs[H_];
    __shared__ float partial[4];
    int b = blockIdx.x;
    int tid = threadIdx.x;
    for (int j = tid; j < H_; j += 256) hs[j] = hlast[(size_t)b * H_ + j];
    __syncthreads();
    float z = 0.f;
    const float* w = W1 + (size_t)tid * H_;
    for (int j = 0; j < H_; j++) z += hs[j] * w[j];
    z += b1[tid];
    z = z / (1.0f + fabsf(z));
    float p = z * W2[tid];
    #pragma unroll
    for (int off = 32; off > 0; off >>= 1) p += __shfl_down(p, off, 64);
    if ((tid & 63) == 0) partial[tid >> 6] = p;
    __syncthreads();
    if (tid == 0) {
        float s = partial[0] + partial[1] + partial[2] + partial[3];
        out[b] = (s + b2[0]) * 70.0f;
    }
}

extern "C" void kernel_launch(void* const* d_in, const int* in_sizes, int n_in,
                              void* d_out, int out_size, void* d_ws, size_t ws_size,
                              hipStream_t stream) {
    const float* x    = (const float*)d_in[0];
    const float* Wih0 = (const float*)d_in[1];
    const float* Whh0 = (const float*)d_in[2];
    const float* bih0 = (const float*)d_in[3];
    const float* bhh0 = (const float*)d_in[4];
    const float* Wih1 = (const float*)d_in[5];
    const float* Whh1 = (const float*)d_in[6];
    const float* bih1 = (const float*)d_in[7];
    const float* bhh1 = (const float*)d_in[8];
    const float* W1   = (const float*)d_in[9];
    const float* b1   = (const float*)d_in[10];
    const float* W2   = (const float*)d_in[11];
    const float* b2   = (const float*)d_in[12];
    float* out = (float*)d_out;

    const size_t RING = (size_t)T_ * 4 * GSLOT_ * 2;   // 24 MB each

    char* w = (char*)d_ws;
    int* ctrs = (int*)w;                          w += 65536;
    unsigned short* h1loc = (unsigned short*)w;   w += RING;
    unsigned short* h1x   = (unsigned short*)w;   w += RING;
    unsigned short* h2loc = (unsigned short*)w;   w += RING;
    unsigned short* xsT   = (unsigned short*)w;   w += (size_t)B_ * T_ * IN_ * 2;
    unsigned short* W0cat = (unsigned short*)w;   w += (size_t)G_ * K0_ * 2;
    unsigned short* W1cat = (unsigned short*)w;   w += (size_t)G_ * K1_ * 2;
    float* bias0 = (float*)w;                     w += G_ * 4;
    float* bias1 = (float*)w;                     w += G_ * 4;
    float* hf32  = (float*)w;                     w += (size_t)B_ * H_ * 4;

    prep_kernel<<<1024, 256, 0, stream>>>(x, Wih0, Whh0, bih0, bhh0,
                                          Wih1, Whh1, bih1, bhh1,
                                          xsT, W0cat, W1cat, bias0, bias1, ctrs);
    lstm_persistent<<<NWGT, 256, 0, stream>>>(xsT, W0cat, W1cat, bias0, bias1,
                                              h1loc, h1x, h2loc, hf32, ctrs);
    head_kernel<<<B_, 256, 0, stream>>>(hf32, W1, b1, W2, b2, out);
}